// Round 1
// 69.663 us; speedup vs baseline: 1.0502x; 1.0502x over previous
//
#include <hip/hip_runtime.h>
#include <math.h>

#define N_OCT  32
#define N_SMP  32768
#define N_PAIR 64          // B*E = 4*16
#define BPP    32          // blocks per pair: 1024 samples/block, 4/thread

// ---------------------------------------------------------------------------
// Kernel 1: oscillator bank.
//  R7 change: the Nyquist mask (f0s < 1) is a monotone per-pair cutoff
//  (factors are a harmonic ramp), so octaves >= kmax contribute EXACT +0.
//  Census of the input distribution says ~7/32 octaves are active on
//  average -> the old full-32 loop wasted ~75% of its sin work. We count
//  active octaves in the prologue (ballot) and loop only over
//  ceil(kmax/4) float4 groups, reading (w,a) from LDS per group
//  (same-address broadcast, conflict-free). This is bit-identical to the
//  full loop: skipped terms are fma(a, +0, acc) == acc, and acc can never
//  be -0. Dropping the 64-VGPR preload also roughly halves VGPR count ->
//  higher occupancy for the trans-pipe-bound inner loop.
//  Prologue keeps the reference's EXACT sequential fp32 cumsum rounding.
//  Body keeps 4 independent FMA chains (R6: serial recurrence not faster).
// ---------------------------------------------------------------------------
__global__ __launch_bounds__(256) void f0res_osc(
    const float* __restrict__ f0_in,
    const float* __restrict__ dec_in,
    const float* __restrict__ fs_in,
    float* __restrict__ out,
    float* __restrict__ bmax)        // [N_PAIR][BPP]
{
    __shared__ __align__(16) float sw[N_OCT];
    __shared__ __align__(16) float sa[N_OCT];
    __shared__ int s_ng;

    const int pair = blockIdx.x >> 5;
    const int blk  = blockIdx.x & (BPP - 1);
    const int tid  = threadIdx.x;

    // ---- in-block setup (lanes 0-31 of wave 0) ----
    if (tid < N_OCT) {
        const float minf   = (float)(20.0 / 11025.0);
        const float frange = (float)(3000.0 / 11025.0 - 20.0 / 11025.0);
        const float pif    = 3.14159265358979323846f;
        const float INV2PI = 0.15915494309189535f;

        float f0 = fabsf(f0_in[pair]);
        float fs = fs_in[pair];
        float x  = dec_in[pair];

        float s1 = 1.0f / (1.0f + expf(-x));      // double sigmoid (ref quirk)
        float s2 = 1.0f / (1.0f + expf(-s1));
        float d  = 0.01f + s2 * (float)(0.99 * 0.99);
        float ld = logf(d + 1e-12f);
        float f0p = (minf + f0 * frange) * pif;

        // sequential fp32 cumsums — bit-match the reference rounding order
        float fac = 0.0f, acl = 0.0f, myfac = 0.0f, myacl = 0.0f;
#pragma unroll
        for (int o = 0; o < N_OCT; ++o) {
            fac += fs;
            acl += ld;
            if (o == tid) { myfac = fac; myacl = acl; }
        }
        float f0s = f0p * myfac;
        const bool act = (f0s < 1.0f);            // monotone -> prefix mask
        sw[tid] = act ? f0s * INV2PI : 0.0f;      // revolutions; sin(0)=0
        sa[tid] = expf(myacl);                    // d^(o+1)

        unsigned long long bal = __ballot(act);   // lanes 32-63 inactive -> 0
        if (tid == 0) s_ng = (__popcll(bal) + 3) >> 2;   // active float4 groups
    }
    __syncthreads();

    const int ng = s_ng;                          // uniform per block

    const int   s0 = (blk << 10) + tid;           // samples s0 + {0,256,512,768}
    const float t0 = (float)(s0 + 1);             // t = s+1, exact in fp32
    const float t1 = (float)(s0 + 257);
    const float t2 = (float)(s0 + 513);
    const float t3 = (float)(s0 + 769);

    float acc0 = 0.0f, acc1 = 0.0f, acc2 = 0.0f, acc3 = 0.0f;

    const float4* w4 = (const float4*)sw;
    const float4* a4 = (const float4*)sa;
    for (int i = 0; i < ng; ++i) {
        const float4 wv = w4[i];                  // ds_read_b128 broadcast
        const float4 av = a4[i];
        const float wr[4] = { wv.x, wv.y, wv.z, wv.w };
        const float ar[4] = { av.x, av.y, av.z, av.w };
#pragma unroll
        for (int j = 0; j < 4; ++j) {
            const float w = wr[j], a = ar[j];
            acc0 = fmaf(a, __builtin_amdgcn_sinf(__builtin_amdgcn_fractf(w * t0)), acc0);
            acc1 = fmaf(a, __builtin_amdgcn_sinf(__builtin_amdgcn_fractf(w * t1)), acc1);
            acc2 = fmaf(a, __builtin_amdgcn_sinf(__builtin_amdgcn_fractf(w * t2)), acc2);
            acc3 = fmaf(a, __builtin_amdgcn_sinf(__builtin_amdgcn_fractf(w * t3)), acc3);
        }
    }

    float* op = out + pair * N_SMP + s0;
    op[0]   = acc0;
    op[256] = acc1;
    op[512] = acc2;
    op[768] = acc3;

    // ---- block max -> one plain store (no atomics, no init needed) ----
    float av_ = fmaxf(fmaxf(fabsf(acc0), fabsf(acc1)),
                      fmaxf(fabsf(acc2), fabsf(acc3)));
#pragma unroll
    for (int m = 32; m >= 1; m >>= 1)
        av_ = fmaxf(av_, __shfl_xor(av_, m, 64));
    __shared__ float wm[4];
    if ((tid & 63) == 0) wm[tid >> 6] = av_;
    __syncthreads();
    if (tid == 0)
        bmax[pair * BPP + blk] = fmaxf(fmaxf(wm[0], wm[1]), fmaxf(wm[2], wm[3]));
}

// ---------------------------------------------------------------------------
// Kernel 2: reduce the 32 per-block maxes, then normalize (float4, L2-hot).
// ---------------------------------------------------------------------------
__global__ __launch_bounds__(256) void f0res_norm(
    float* __restrict__ out, const float* __restrict__ bmax)
{
    const int pair = blockIdx.x >> 5;                   // 32 blocks per pair
    const int tid  = threadIdx.x;

    float v = (tid < BPP) ? bmax[pair * BPP + tid] : 0.0f;
#pragma unroll
    for (int m = 16; m >= 1; m >>= 1)
        v = fmaxf(v, __shfl_xor(v, m, 64));
    __shared__ float smx;
    if (tid == 0) smx = v;
    __syncthreads();
    const float inv = 1.0f / (smx + 1e-8f);

    const int idx = ((blockIdx.x & 31) << 8) + tid;     // 256 float4 per block
    float4* o4 = (float4*)(out + pair * N_SMP);
    float4 val = o4[idx];
    val.x *= inv; val.y *= inv; val.z *= inv; val.w *= inv;
    o4[idx] = val;
}

extern "C" void kernel_launch(void* const* d_in, const int* in_sizes, int n_in,
                              void* d_out, int out_size, void* d_ws, size_t ws_size,
                              hipStream_t stream) {
    const float* f0  = (const float*)d_in[0];
    const float* dec = (const float*)d_in[1];
    const float* fs  = (const float*)d_in[2];
    float* out = (float*)d_out;

    float* bmax = (float*)d_ws;                 // 64*32 floats

    f0res_osc <<<N_PAIR * BPP, 256, 0, stream>>>(f0, dec, fs, out, bmax);
    f0res_norm<<<N_PAIR * 32,  256, 0, stream>>>(out, bmax);
}